// Round 1
// baseline (7603.036 us; speedup 1.0000x reference)
//
#include <hip/hip_runtime.h>
#include <math.h>

#define D_MODEL 1024
#define N_LAYER 2
#define VOCAB   32000
#define D_STATE 16
#define D_INNER 2048
#define DT_RANK 64
#define D_CONV  4
#define BB      2
#define LL      1024
#define TT      (BB*LL)

// ---------------------------------------------------------------------------
// Embedding gather: x[t,:] = emb[ids[t],:]
// grid = TT blocks, 256 threads; each thread copies one float4 (1024 floats/row)
// ---------------------------------------------------------------------------
__global__ __launch_bounds__(256) void embed_kernel(
    const int* __restrict__ ids, const float* __restrict__ emb,
    float* __restrict__ x) {
  int t  = blockIdx.x;
  int id = ids[t];
  const float4* src = (const float4*)(emb + (size_t)id * D_MODEL);
  float4*       dst = (float4*)(x + (size_t)t * D_MODEL);
  dst[threadIdx.x] = src[threadIdx.x];
}

// ---------------------------------------------------------------------------
// RMSNorm: o[t,:] = x[t,:] * rsqrt(mean(x^2)+eps) * w
// grid = TT blocks, 256 threads, each thread owns one float4
// ---------------------------------------------------------------------------
__global__ __launch_bounds__(256) void rmsnorm_kernel(
    const float* __restrict__ x, const float* __restrict__ w,
    float* __restrict__ o) {
  int t = blockIdx.x;
  const float4* xr = (const float4*)(x + (size_t)t * D_MODEL);
  float4 v = xr[threadIdx.x];
  float ss = v.x*v.x + v.y*v.y + v.z*v.z + v.w*v.w;
  // wave-64 butterfly reduce
  for (int off = 32; off > 0; off >>= 1) ss += __shfl_down(ss, off, 64);
  __shared__ float wsum[4];
  if ((threadIdx.x & 63) == 0) wsum[threadIdx.x >> 6] = ss;
  __syncthreads();
  float tot = wsum[0] + wsum[1] + wsum[2] + wsum[3];
  float scale = rsqrtf(tot / (float)D_MODEL + 1e-5f);
  float4 wv = ((const float4*)w)[threadIdx.x];
  float4 ov;
  ov.x = v.x * scale * wv.x;
  ov.y = v.y * scale * wv.y;
  ov.z = v.z * scale * wv.z;
  ov.w = v.w * scale * wv.w;
  ((float4*)(o + (size_t)t * D_MODEL))[threadIdx.x] = ov;
}

// ---------------------------------------------------------------------------
// Tiled fp32 GEMM (NT): C[m,n] = sum_k A[m,k] * B[n,k]  (+ optional residual)
// 64x64 tile, TK=16, 256 threads, 4x4 accumulators per thread.
// ---------------------------------------------------------------------------
#define TM 64
#define TN 64
#define TK 16

__global__ __launch_bounds__(256) void gemm_nt(
    const float* __restrict__ A, int lda,
    const float* __restrict__ B, int ldb,
    float* __restrict__ C, int ldc,
    int M, int N, int K,
    const float* __restrict__ resid) {
  __shared__ __align__(16) float As[TK][TM + 4];
  __shared__ __align__(16) float Bs[TK][TN + 4];
  int tid = threadIdx.x;
  int bm  = blockIdx.y * TM;
  int bn  = blockIdx.x * TN;
  int tm  = (tid >> 4) * 4;   // 0..60
  int tn  = (tid & 15) * 4;   // 0..60
  float acc[4][4] = {};

  for (int k0 = 0; k0 < K; k0 += TK) {
#pragma unroll
    for (int i = 0; i < 4; i++) {
      int idx = tid + i * 256;      // 0..1023
      int r   = idx >> 4;           // 0..63
      int kk  = idx & 15;
      int gm  = bm + r;
      As[kk][r] = (gm < M) ? A[(size_t)gm * lda + k0 + kk] : 0.f;
      int gn  = bn + r;
      Bs[kk][r] = (gn < N) ? B[(size_t)gn * ldb + k0 + kk] : 0.f;
    }
    __syncthreads();
#pragma unroll
    for (int kk = 0; kk < TK; kk++) {
      float4 av = *(const float4*)&As[kk][tm];
      float4 bv = *(const float4*)&Bs[kk][tn];
      acc[0][0] += av.x * bv.x; acc[0][1] += av.x * bv.y;
      acc[0][2] += av.x * bv.z; acc[0][3] += av.x * bv.w;
      acc[1][0] += av.y * bv.x; acc[1][1] += av.y * bv.y;
      acc[1][2] += av.y * bv.z; acc[1][3] += av.y * bv.w;
      acc[2][0] += av.z * bv.x; acc[2][1] += av.z * bv.y;
      acc[2][2] += av.z * bv.z; acc[2][3] += av.z * bv.w;
      acc[3][0] += av.w * bv.x; acc[3][1] += av.w * bv.y;
      acc[3][2] += av.w * bv.z; acc[3][3] += av.w * bv.w;
    }
    __syncthreads();
  }

#pragma unroll
  for (int i = 0; i < 4; i++) {
    int gm = bm + tm + i;
    if (gm < M) {
#pragma unroll
      for (int j = 0; j < 4; j++) {
        int gn = bn + tn + j;
        if (gn < N) {
          size_t o = (size_t)gm * ldc + gn;
          float r = resid ? resid[o] : 0.f;
          C[o] = acc[i][j] + r;
        }
      }
    }
  }
}

// ---------------------------------------------------------------------------
// Depthwise causal conv (width 4) + bias + SiLU
// one thread per (t, j); grid covers TT*D_INNER elements
// ---------------------------------------------------------------------------
__global__ __launch_bounds__(256) void conv_silu_kernel(
    const float* __restrict__ xi, const float* __restrict__ cw,
    const float* __restrict__ cb, float* __restrict__ u) {
  size_t idx = (size_t)blockIdx.x * 256 + threadIdx.x;
  int j = (int)(idx & (D_INNER - 1));
  int t = (int)(idx >> 11);          // D_INNER = 2^11
  int b = t >> 10;                   // LL = 1024
  int l = t & (LL - 1);
  float acc = cb[j];
#pragma unroll
  for (int k = 0; k < D_CONV; k++) {
    int ls = l - (D_CONV - 1) + k;
    if (ls >= 0)
      acc += xi[((size_t)b * LL + ls) * D_INNER + j] * cw[j * D_CONV + k];
  }
  float sig = 1.f / (1.f + expf(-acc));
  u[idx] = acc * sig;
}

// ---------------------------------------------------------------------------
// Selective scan + skip (u*D) + gate (silu(res)), fused.
// One thread per (b, d) chain; states for n=0..15 in registers.
// delta_raw comes in pre-softplus. Writes gated y over the `res` buffer.
// grid = (D_INNER/256, BB)
// ---------------------------------------------------------------------------
__global__ __launch_bounds__(256) void scan_kernel(
    const float* __restrict__ draw,   // (TT, D_INNER) pre-softplus delta
    const float* __restrict__ u,      // (TT, D_INNER)
    const float* __restrict__ xdbl,   // (TT, 96): [0:64) dlt, [64:80) B, [80:96) C
    const float* __restrict__ Alog,   // (D_INNER, D_STATE)
    const float* __restrict__ Dp,     // (D_INNER)
    float* __restrict__ resyg) {      // in: res (gate); out: gated y
  int d = blockIdx.x * 256 + threadIdx.x;
  int b = blockIdx.y;
  float A[D_STATE];
#pragma unroll
  for (int n = 0; n < D_STATE; n++)
    A[n] = -expf(Alog[(size_t)d * D_STATE + n]);
  float Dv = Dp[d];
  float st[D_STATE];
#pragma unroll
  for (int n = 0; n < D_STATE; n++) st[n] = 0.f;

  for (int l = 0; l < LL; l++) {
    size_t t  = (size_t)b * LL + l;
    size_t td = t * D_INNER + d;
    float dr = draw[td];
    float uv = u[td];
    // stable softplus
    float dlt = fmaxf(dr, 0.f) + log1pf(expf(-fabsf(dr)));
    float du  = dlt * uv;
    const float4* bm4 = (const float4*)(xdbl + t * 96 + DT_RANK);
    const float4* cm4 = (const float4*)(xdbl + t * 96 + DT_RANK + D_STATE);
    float y = 0.f;
#pragma unroll
    for (int q = 0; q < 4; q++) {
      float4 bm = bm4[q];
      float4 cm = cm4[q];
      float e;
      e = expf(dlt * A[4*q+0]); st[4*q+0] = e * st[4*q+0] + du * bm.x; y += st[4*q+0] * cm.x;
      e = expf(dlt * A[4*q+1]); st[4*q+1] = e * st[4*q+1] + du * bm.y; y += st[4*q+1] * cm.y;
      e = expf(dlt * A[4*q+2]); st[4*q+2] = e * st[4*q+2] + du * bm.z; y += st[4*q+2] * cm.z;
      e = expf(dlt * A[4*q+3]); st[4*q+3] = e * st[4*q+3] + du * bm.w; y += st[4*q+3] * cm.w;
    }
    float rv  = resyg[td];
    float sig = 1.f / (1.f + expf(-rv));
    resyg[td] = (y + uv * Dv) * (rv * sig);
  }
}

// ---------------------------------------------------------------------------
// Driver
// ---------------------------------------------------------------------------
extern "C" void kernel_launch(void* const* d_in, const int* in_sizes, int n_in,
                              void* d_out, int out_size, void* d_ws, size_t ws_size,
                              hipStream_t stream) {
  const int*   ids    = (const int*)  d_in[0];
  const float* emb    = (const float*)d_in[1];
  const float* normfw = (const float*)d_in[2];
  const float* Winl   = (const float*)d_in[3];
  const float* Winr   = (const float*)d_in[4];
  const float* convw  = (const float*)d_in[5];
  const float* convb  = (const float*)d_in[6];
  const float* Wx     = (const float*)d_in[7];
  const float* Wdt    = (const float*)d_in[8];
  const float* Alog   = (const float*)d_in[9];
  const float* Dp     = (const float*)d_in[10];
  const float* Wout   = (const float*)d_in[11];
  const float* normw  = (const float*)d_in[12];
  float* out = (float*)d_out;

  float* ws   = (float*)d_ws;
  float* x    = ws;                      // TT*D_MODEL   (residual stream)
  float* xn   = x    + (size_t)TT * D_MODEL;   // TT*D_MODEL
  float* xi   = xn   + (size_t)TT * D_MODEL;   // TT*D_INNER (also delta_raw)
  float* res  = xi   + (size_t)TT * D_INNER;   // TT*D_INNER (also gated y)
  float* u    = res  + (size_t)TT * D_INNER;   // TT*D_INNER
  float* xdbl = u    + (size_t)TT * D_INNER;   // TT*96

  embed_kernel<<<TT, 256, 0, stream>>>(ids, emb, x);

  for (int i = 0; i < N_LAYER; i++) {
    const float* Wl  = Winl  + (size_t)i * D_INNER * D_MODEL;
    const float* Wr  = Winr  + (size_t)i * D_INNER * D_MODEL;
    const float* cw  = convw + (size_t)i * D_INNER * D_CONV;
    const float* cb  = convb + (size_t)i * D_INNER;
    const float* Wxl = Wx    + (size_t)i * (DT_RANK + 2*D_STATE) * D_INNER;
    const float* Wdl = Wdt   + (size_t)i * D_INNER * DT_RANK;
    const float* Al  = Alog  + (size_t)i * D_INNER * D_STATE;
    const float* Dpl = Dp    + (size_t)i * D_INNER;
    const float* Wo  = Wout  + (size_t)i * D_MODEL * D_INNER;
    const float* nw  = normw + (size_t)i * D_MODEL;

    rmsnorm_kernel<<<TT, 256, 0, stream>>>(x, nw, xn);
    // xi = xn @ Wl^T   (TT x D_INNER, K=D_MODEL)
    gemm_nt<<<dim3(D_INNER/TN, TT/TM), 256, 0, stream>>>(
        xn, D_MODEL, Wl, D_MODEL, xi, D_INNER, TT, D_INNER, D_MODEL, nullptr);
    // res = xn @ Wr^T
    gemm_nt<<<dim3(D_INNER/TN, TT/TM), 256, 0, stream>>>(
        xn, D_MODEL, Wr, D_MODEL, res, D_INNER, TT, D_INNER, D_MODEL, nullptr);
    // u = silu(causal_conv(xi) + cb)
    conv_silu_kernel<<<(TT * D_INNER) / 256, 256, 0, stream>>>(xi, cw, cb, u);
    // xdbl = u @ Wx^T   (TT x 96, K=D_INNER)
    gemm_nt<<<dim3((96 + TN - 1)/TN, TT/TM), 256, 0, stream>>>(
        u, D_INNER, Wxl, D_INNER, xdbl, 96, TT, 96, D_INNER, nullptr);
    // delta_raw = xdbl[:, :64] @ Wdt^T   (TT x D_INNER, K=64) -> reuse xi
    gemm_nt<<<dim3(D_INNER/TN, TT/TM), 256, 0, stream>>>(
        xdbl, 96, Wdl, DT_RANK, xi, D_INNER, TT, D_INNER, DT_RANK, nullptr);
    // fused selective scan + skip + gate -> writes over res
    scan_kernel<<<dim3(D_INNER/256, BB), 256, 0, stream>>>(
        xi, u, xdbl, Al, Dpl, res);
    // x = res @ Wo^T + x   (TT x D_MODEL, K=D_INNER)
    gemm_nt<<<dim3(D_MODEL/TN, TT/TM), 256, 0, stream>>>(
        res, D_INNER, Wo, D_INNER, x, D_MODEL, TT, D_MODEL, D_INNER, x);
  }

  rmsnorm_kernel<<<TT, 256, 0, stream>>>(x, normfw, xn);
  // logits = xn @ emb^T   (TT x VOCAB, K=D_MODEL)
  gemm_nt<<<dim3(VOCAB/TN, TT/TM), 256, 0, stream>>>(
      xn, D_MODEL, emb, D_MODEL, out, VOCAB, TT, VOCAB, D_MODEL, nullptr);
}

// Round 2
// 2656.927 us; speedup vs baseline: 2.8616x; 2.8616x over previous
//
#include <hip/hip_runtime.h>
#include <math.h>

#define D_MODEL 1024
#define N_LAYER 2
#define VOCAB   32000
#define D_STATE 16
#define D_INNER 2048
#define DT_RANK 64
#define D_CONV  4
#define BB      2
#define LL      1024
#define TT      (BB*LL)

typedef __attribute__((ext_vector_type(8))) short bf16x8;   // 8 bf16 = 4 VGPRs
typedef __attribute__((ext_vector_type(4))) float f32x4;    // MFMA C/D

// fp32 -> bf16 round-to-nearest-even (bit pattern)
static __device__ __forceinline__ unsigned short bfr(float f) {
  unsigned int u = __float_as_uint(f);
  return (unsigned short)((u + 0x7FFFu + ((u >> 16) & 1u)) >> 16);
}
static __device__ __forceinline__ float b2f(unsigned short h) {
  return __uint_as_float((unsigned int)h << 16);
}
static __device__ __forceinline__ unsigned int pack2(float a, float b) {
  return (unsigned int)bfr(a) | ((unsigned int)bfr(b) << 16);
}

// ---------------------------------------------------------------------------
// Embedding gather: x[t,:] = emb[ids[t],:]  (fp32 residual stream)
// ---------------------------------------------------------------------------
__global__ __launch_bounds__(256) void embed_kernel(
    const int* __restrict__ ids, const float* __restrict__ emb,
    float* __restrict__ x) {
  int t  = blockIdx.x;
  int id = ids[t];
  const float4* src = (const float4*)(emb + (size_t)id * D_MODEL);
  float4*       dst = (float4*)(x + (size_t)t * D_MODEL);
  dst[threadIdx.x] = src[threadIdx.x];
}

// ---------------------------------------------------------------------------
// RMSNorm -> bf16 output (consumed only by MFMA GEMMs)
// ---------------------------------------------------------------------------
__global__ __launch_bounds__(256) void rmsnorm_bf_kernel(
    const float* __restrict__ x, const float* __restrict__ w,
    unsigned short* __restrict__ o) {
  int t = blockIdx.x;
  const float4* xr = (const float4*)(x + (size_t)t * D_MODEL);
  float4 v = xr[threadIdx.x];
  float ss = v.x*v.x + v.y*v.y + v.z*v.z + v.w*v.w;
  for (int off = 32; off > 0; off >>= 1) ss += __shfl_down(ss, off, 64);
  __shared__ float wsum[4];
  if ((threadIdx.x & 63) == 0) wsum[threadIdx.x >> 6] = ss;
  __syncthreads();
  float tot = wsum[0] + wsum[1] + wsum[2] + wsum[3];
  float scale = rsqrtf(tot / (float)D_MODEL + 1e-5f);
  float4 wv = ((const float4*)w)[threadIdx.x];
  ushort4 ov;
  ov.x = bfr(v.x * scale * wv.x);
  ov.y = bfr(v.y * scale * wv.y);
  ov.z = bfr(v.z * scale * wv.z);
  ov.w = bfr(v.w * scale * wv.w);
  ((ushort4*)(o + (size_t)t * D_MODEL))[threadIdx.x] = ov;
}

// ---------------------------------------------------------------------------
// bf16 MFMA GEMM (NT): C[m,n] = sum_k A[m,k]*B[n,k] (+resid)
// BM=BN=128, BK=32, 256 threads = 4 waves in 2x2, each wave 64x64 (16 MFMA tiles).
// A/B sources are bf16 (ABF/BBF=true) or fp32 converted during LDS staging.
// M must be a multiple of 128 (true for all uses: M=2048). N checked.
// LDS rows padded to 40 bf16 (80B) -> conflict-free ds_read_b128.
// ---------------------------------------------------------------------------
#define GBM 128
#define GBN 128
#define GBK 32
#define LDK 40

template<bool BF>
static __device__ __forceinline__ void stage8(short* dst, const void* src, int ld,
                                              int grow, int gcol, bool valid) {
  uint4 w = make_uint4(0u, 0u, 0u, 0u);
  if (valid) {
    if constexpr (BF) {
      w = *(const uint4*)((const unsigned short*)src + (size_t)grow * ld + gcol);
    } else {
      const float* p = (const float*)src + (size_t)grow * ld + gcol;
      float4 v0 = *(const float4*)p;
      float4 v1 = *(const float4*)(p + 4);
      w.x = pack2(v0.x, v0.y); w.y = pack2(v0.z, v0.w);
      w.z = pack2(v1.x, v1.y); w.w = pack2(v1.z, v1.w);
    }
  }
  *(uint4*)dst = w;
}

template<bool ABF, bool BBF, bool RESID>
__global__ __launch_bounds__(256) void gemm_mfma(
    const void* __restrict__ Av, int lda,
    const void* __restrict__ Bv, int ldb,
    float* __restrict__ C, int ldc,
    int N, int K, const float* __restrict__ resid) {
  __shared__ short As[GBM * LDK];
  __shared__ short Bs[GBN * LDK];
  const int tid  = threadIdx.x;
  const int lane = tid & 63;
  const int wid  = tid >> 6;
  const int wm   = (wid >> 1) * 64;
  const int wn   = (wid & 1) * 64;
  const int bm   = blockIdx.y * GBM;
  const int bn   = blockIdx.x * GBN;

  f32x4 acc[4][4] = {};

  const int r0 = tid >> 2;          // 0..63
  const int cg = (tid & 3) * 8;     // 0,8,16,24
  const int fm = wm + (lane & 15);
  const int fn = wn + (lane & 15);
  const int fk = (lane >> 4) * 8;

  for (int k0 = 0; k0 < K; k0 += GBK) {
    stage8<ABF>(&As[(size_t)r0 * LDK + cg],        Av, lda, bm + r0,      k0 + cg, true);
    stage8<ABF>(&As[(size_t)(r0 + 64) * LDK + cg], Av, lda, bm + r0 + 64, k0 + cg, true);
    stage8<BBF>(&Bs[(size_t)r0 * LDK + cg],        Bv, ldb, bn + r0,      k0 + cg, (bn + r0) < N);
    stage8<BBF>(&Bs[(size_t)(r0 + 64) * LDK + cg], Bv, ldb, bn + r0 + 64, k0 + cg, (bn + r0 + 64) < N);
    __syncthreads();

    bf16x8 aq[4], bq[4];
#pragma unroll
    for (int i = 0; i < 4; i++) aq[i] = *(const bf16x8*)&As[(size_t)(fm + 16 * i) * LDK + fk];
#pragma unroll
    for (int i = 0; i < 4; i++) bq[i] = *(const bf16x8*)&Bs[(size_t)(fn + 16 * i) * LDK + fk];
#pragma unroll
    for (int mt = 0; mt < 4; mt++)
#pragma unroll
      for (int nt = 0; nt < 4; nt++)
        acc[mt][nt] = __builtin_amdgcn_mfma_f32_16x16x32_bf16(
            aq[mt], bq[nt], acc[mt][nt], 0, 0, 0);
    __syncthreads();
  }

  // C/D layout (verified m89/m91): col = lane&15, row = (lane>>4)*4 + reg
  const int col   = lane & 15;
  const int rbase = (lane >> 4) * 4;
#pragma unroll
  for (int mt = 0; mt < 4; mt++) {
#pragma unroll
    for (int nt = 0; nt < 4; nt++) {
      int gn = bn + wn + nt * 16 + col;
      if (gn < N) {
        int gm = bm + wm + mt * 16 + rbase;
#pragma unroll
        for (int i = 0; i < 4; i++) {
          size_t o = (size_t)(gm + i) * ldc + gn;
          float r = RESID ? resid[o] : 0.f;
          C[o] = acc[mt][nt][i] + r;
        }
      }
    }
  }
}

// ---------------------------------------------------------------------------
// Depthwise causal conv (width 4) + bias + SiLU  -> bf16 u
// ---------------------------------------------------------------------------
__global__ __launch_bounds__(256) void conv_silu_kernel(
    const float* __restrict__ xi, const float* __restrict__ cw,
    const float* __restrict__ cb, unsigned short* __restrict__ u) {
  size_t idx = (size_t)blockIdx.x * 256 + threadIdx.x;
  int j = (int)(idx & (D_INNER - 1));
  int t = (int)(idx >> 11);
  int b = t >> 10;
  int l = t & (LL - 1);
  float acc = cb[j];
#pragma unroll
  for (int k = 0; k < D_CONV; k++) {
    int ls = l - (D_CONV - 1) + k;
    if (ls >= 0)
      acc += xi[((size_t)b * LL + ls) * D_INNER + j] * cw[j * D_CONV + k];
  }
  float sig = 1.f / (1.f + __expf(-acc));
  u[idx] = bfr(acc * sig);
}

// ---------------------------------------------------------------------------
// Selective scan + skip + gate, fused. One thread per (b,d) chain.
// 64-thread blocks (64 blocks total), next-iteration prefetch to overlap
// the transcendental chain with global loads. Writes gated y as bf16.
// ---------------------------------------------------------------------------
__global__ __launch_bounds__(64) void scan_kernel(
    const float* __restrict__ draw,           // (TT, D_INNER) pre-softplus delta
    const unsigned short* __restrict__ ub,    // (TT, D_INNER) bf16 u
    const float* __restrict__ xdbl,           // (TT, 128): [64:80)=B, [80:96)=C
    const float* __restrict__ Alog,           // (D_INNER, 16)
    const float* __restrict__ Dp,             // (D_INNER)
    const float* __restrict__ res,            // (TT, D_INNER) gate input
    unsigned short* __restrict__ yg) {        // (TT, D_INNER) bf16 out
  int d = blockIdx.x * 64 + threadIdx.x;
  int b = blockIdx.y;
  float A[D_STATE];
#pragma unroll
  for (int n = 0; n < D_STATE; n++)
    A[n] = -__expf(Alog[(size_t)d * D_STATE + n] * 1.44269504f); // exp via exp2
  float Dv = Dp[d];
  float st[D_STATE];
#pragma unroll
  for (int n = 0; n < D_STATE; n++) st[n] = 0.f;

  size_t t0  = (size_t)b * LL;
  size_t td  = t0 * D_INNER + d;
  float dr = draw[td];
  float uv = b2f(ub[td]);
  float rv = res[td];
  float4 Bq[4], Cq[4];
#pragma unroll
  for (int q = 0; q < 4; q++) {
    Bq[q] = *(const float4*)(xdbl + t0 * 128 + 64 + 4 * q);
    Cq[q] = *(const float4*)(xdbl + t0 * 128 + 80 + 4 * q);
  }

  for (int l = 0; l < LL; l++) {
    // prefetch next iteration (clamped at the end; values unused then)
    int ln = (l + 1 < LL) ? (l + 1) : l;
    size_t tn  = t0 + ln;
    size_t tdn = tn * D_INNER + d;
    float drn = draw[tdn];
    float uvn = b2f(ub[tdn]);
    float rvn = res[tdn];
    float4 Bn[4], Cn[4];
#pragma unroll
    for (int q = 0; q < 4; q++) {
      Bn[q] = *(const float4*)(xdbl + tn * 128 + 64 + 4 * q);
      Cn[q] = *(const float4*)(xdbl + tn * 128 + 80 + 4 * q);
    }

    // softplus (stable)
    float dlt = fmaxf(dr, 0.f) + log1pf(__expf(-fabsf(dr)));
    float du  = dlt * uv;
    float y = 0.f;
#pragma unroll
    for (int q = 0; q < 4; q++) {
      float e;
      e = __expf(dlt * A[4*q+0]); st[4*q+0] = e * st[4*q+0] + du * Bq[q].x; y += st[4*q+0] * Cq[q].x;
      e = __expf(dlt * A[4*q+1]); st[4*q+1] = e * st[4*q+1] + du * Bq[q].y; y += st[4*q+1] * Cq[q].y;
      e = __expf(dlt * A[4*q+2]); st[4*q+2] = e * st[4*q+2] + du * Bq[q].z; y += st[4*q+2] * Cq[q].z;
      e = __expf(dlt * A[4*q+3]); st[4*q+3] = e * st[4*q+3] + du * Bq[q].w; y += st[4*q+3] * Cq[q].w;
    }
    float sig = 1.f / (1.f + __expf(-rv));
    size_t tdc = (t0 + l) * D_INNER + d;
    yg[tdc] = bfr((y + uv * Dv) * (rv * sig));

    dr = drn; uv = uvn; rv = rvn;
#pragma unroll
    for (int q = 0; q < 4; q++) { Bq[q] = Bn[q]; Cq[q] = Cn[q]; }
  }
}

// ---------------------------------------------------------------------------
// Driver
// ---------------------------------------------------------------------------
extern "C" void kernel_launch(void* const* d_in, const int* in_sizes, int n_in,
                              void* d_out, int out_size, void* d_ws, size_t ws_size,
                              hipStream_t stream) {
  const int*   ids    = (const int*)  d_in[0];
  const float* emb    = (const float*)d_in[1];
  const float* normfw = (const float*)d_in[2];
  const float* Winl   = (const float*)d_in[3];
  const float* Winr   = (const float*)d_in[4];
  const float* convw  = (const float*)d_in[5];
  const float* convb  = (const float*)d_in[6];
  const float* Wx     = (const float*)d_in[7];
  const float* Wdt    = (const float*)d_in[8];
  const float* Alog   = (const float*)d_in[9];
  const float* Dp     = (const float*)d_in[10];
  const float* Wout   = (const float*)d_in[11];
  const float* normw  = (const float*)d_in[12];
  float* out = (float*)d_out;

  // workspace layout (61 MB total)
  float* x    = (float*)d_ws;                        // 2M fp32
  float* xi   = x    + (size_t)TT * D_MODEL;         // 4M fp32 (conv in / delta_raw)
  float* res  = xi   + (size_t)TT * D_INNER;         // 4M fp32 (gate)
  float* xdbl = res  + (size_t)TT * D_INNER;         // TT*128 fp32
  unsigned short* xn_bf = (unsigned short*)(xdbl + (size_t)TT * 128); // 2M bf16
  unsigned short* u_bf  = xn_bf + (size_t)TT * D_MODEL;               // 4M bf16
  unsigned short* yg_bf = u_bf  + (size_t)TT * D_INNER;               // 4M bf16

  embed_kernel<<<TT, 256, 0, stream>>>(ids, emb, x);

  for (int i = 0; i < N_LAYER; i++) {
    const float* Wl  = Winl  + (size_t)i * D_INNER * D_MODEL;
    const float* Wr  = Winr  + (size_t)i * D_INNER * D_MODEL;
    const float* cw  = convw + (size_t)i * D_INNER * D_CONV;
    const float* cb  = convb + (size_t)i * D_INNER;
    const float* Wxl = Wx    + (size_t)i * (DT_RANK + 2*D_STATE) * D_INNER;
    const float* Wdl = Wdt   + (size_t)i * D_INNER * DT_RANK;
    const float* Al  = Alog  + (size_t)i * D_INNER * D_STATE;
    const float* Dpl = Dp    + (size_t)i * D_INNER;
    const float* Wo  = Wout  + (size_t)i * D_MODEL * D_INNER;
    const float* nw  = normw + (size_t)i * D_MODEL;

    rmsnorm_bf_kernel<<<TT, 256, 0, stream>>>(x, nw, xn_bf);
    // xi = xn @ Wl^T    (2048 x 2048, K=1024)
    gemm_mfma<true, false, false><<<dim3(D_INNER/GBN, TT/GBM), 256, 0, stream>>>(
        xn_bf, D_MODEL, Wl, D_MODEL, xi, D_INNER, D_INNER, D_MODEL, nullptr);
    // res = xn @ Wr^T
    gemm_mfma<true, false, false><<<dim3(D_INNER/GBN, TT/GBM), 256, 0, stream>>>(
        xn_bf, D_MODEL, Wr, D_MODEL, res, D_INNER, D_INNER, D_MODEL, nullptr);
    // u = silu(conv(xi)+cb) -> bf16
    conv_silu_kernel<<<(TT * D_INNER) / 256, 256, 0, stream>>>(xi, cw, cb, u_bf);
    // xdbl = u @ Wx^T   (2048 x 96, K=2048), stride 128
    gemm_mfma<true, false, false><<<dim3(1, TT/GBM), 256, 0, stream>>>(
        u_bf, D_INNER, Wxl, D_INNER, xdbl, 128, DT_RANK + 2*D_STATE, D_INNER, nullptr);
    // delta_raw = xdbl[:,:64] @ Wdt^T  (2048 x 2048, K=64) -> xi
    gemm_mfma<false, false, false><<<dim3(D_INNER/GBN, TT/GBM), 256, 0, stream>>>(
        xdbl, 128, Wdl, DT_RANK, xi, D_INNER, D_INNER, DT_RANK, nullptr);
    // fused selective scan + skip + gate -> yg_bf
    scan_kernel<<<dim3(D_INNER/64, BB), 64, 0, stream>>>(
        xi, u_bf, xdbl, Al, Dpl, res, yg_bf);
    // x = yg @ Wo^T + x (2048 x 1024, K=2048)
    gemm_mfma<true, false, true><<<dim3(D_MODEL/GBN, TT/GBM), 256, 0, stream>>>(
        yg_bf, D_INNER, Wo, D_INNER, x, D_MODEL, D_MODEL, D_INNER, x);
  }

  rmsnorm_bf_kernel<<<TT, 256, 0, stream>>>(x, normfw, xn_bf);
  // logits = xn @ emb^T  (2048 x 32000, K=1024)
  gemm_mfma<true, false, false><<<dim3(VOCAB/GBN, TT/GBM), 256, 0, stream>>>(
      xn_bf, D_MODEL, emb, D_MODEL, out, VOCAB, VOCAB, D_MODEL, nullptr);
}